// Round 19
// baseline (97.809 us; speedup 1.0000x reference)
//
#include <hip/hip_runtime.h>
#include <hip/hip_bf16.h>

// PartitionedNormalization: per-domain BN stats (training mode) + affine.
// out[B][128] f32 = (gg+dg[s])*(x-mean[s])*rsqrt(var[s]+eps) + (gb+db[s])
//
// R19: sort-then-reduce. R18's DS-RMW chains are semantically serialized
// (domains may alias) -> sort rows by domain per 2048-chunk (deterministic
// stable counting sort on 1MB seg), then reduce accumulates in REGISTERS
// (domain uniform per half-wave, <=8 runs per 64-row window), flushing to
// a shared 8KB LDS acc only at run boundaries. Zero DS in hot loop.

#define DIM 128
#define NDOM 8
#define PENT (NDOM + 2 * NDOM * DIM)  // 8 counts + 1024 sums + 1024 sqsums = 2056
#define EPSV 1e-3f
#define SORT_ROWS 2048  // rows per sort block
#define RPT 8           // rows per thread in sort (256 thr * 8 = 2048)

// ---------------- pass 0: per-chunk stable counting sort of row indices ----------------
__global__ __launch_bounds__(256) void pn_sort(const int* __restrict__ seg,
                                               int* __restrict__ perm) {
  __shared__ int hist[NDOM * 256];  // [s][t], 8KB
  __shared__ int tot[NDOM];
  __shared__ int base[NDOM];
  const int t = threadIdx.x;
  const int lane = t & 63;
  const int w = t >> 6;  // wave 0..3
  const int chunk0 = blockIdx.x * SORT_ROWS;
  const int r0 = chunk0 + t * RPT;

  for (int i = t; i < NDOM * 256; i += 256) hist[i] = 0;
  __syncthreads();

  // phase 1: per-(domain,thread) counts; only thread t touches column t
#pragma unroll
  for (int j = 0; j < RPT; ++j) {
    const int s = seg[r0 + j];
    hist[s * 256 + t] += 1;
  }
  __syncthreads();

  // phase 2: per-domain exclusive prefix over t (wave w scans domains 2w,2w+1)
#pragma unroll
  for (int ds = 0; ds < 2; ++ds) {
    const int s = 2 * w + ds;
    const int j4 = lane * 4;
    int a0 = hist[s * 256 + j4 + 0];
    int a1 = hist[s * 256 + j4 + 1];
    int a2 = hist[s * 256 + j4 + 2];
    int a3 = hist[s * 256 + j4 + 3];
    const int tsum = a0 + a1 + a2 + a3;
    int inc = tsum;
#pragma unroll
    for (int d = 1; d < 64; d <<= 1) {
      const int y = __shfl_up(inc, d, 64);
      inc = (lane >= d) ? inc + y : inc;
    }
    const int exc = inc - tsum;
    hist[s * 256 + j4 + 0] = exc;
    hist[s * 256 + j4 + 1] = exc + a0;
    hist[s * 256 + j4 + 2] = exc + a0 + a1;
    hist[s * 256 + j4 + 3] = exc + a0 + a1 + a2;
    if (lane == 63) tot[s] = inc;
  }
  __syncthreads();

  if (t == 0) {
    int b = 0;
#pragma unroll
    for (int s = 0; s < NDOM; ++s) { base[s] = b; b += tot[s]; }
  }
  __syncthreads();

  // phase 3: stable scatter (own cell hist[s][t] as running counter)
#pragma unroll
  for (int j = 0; j < RPT; ++j) {
    const int row = r0 + j;
    const int s = seg[row];
    const int idx = s * 256 + t;
    const int pos = hist[idx];
    hist[idx] = pos + 1;
    perm[chunk0 + base[s] + pos] = row;
  }
}

// ---------------- pass 1: register accumulation over sorted rows ----------------
__global__ __launch_bounds__(256) void pn_reduce(const float4* __restrict__ x4,
                                                 const int* __restrict__ seg,
                                                 const int* __restrict__ perm,
                                                 float* __restrict__ partials,
                                                 int rowsPerBlock) {
  __shared__ float acc[2 * NDOM * DIM];  // sums[1024] | sqs[1024], 8KB
  __shared__ float lcnt[NDOM];
  const int tid = threadIdx.x;
  const int w = tid >> 6;
  const int l = tid & 63;
  const int h = l >> 5;    // half-wave
  const int g = l & 31;    // float4 col group
  const int hw = w * 2 + h;

  for (int i = tid; i < 2 * NDOM * DIM; i += 256) acc[i] = 0.f;
  if (tid < NDOM) lcnt[tid] = 0.f;
  __syncthreads();

  const int rowsPerHW = rowsPerBlock >> 3;  // 64 at NB=512
  const int base = blockIdx.x * rowsPerBlock + hw * rowsPerHW;

  float4 sum = make_float4(0.f, 0.f, 0.f, 0.f);
  float4 sq = make_float4(0.f, 0.f, 0.f, 0.f);
  float cnt = 0.f;
  int cur = seg[perm[base]];

#define FLUSH()                                              \
  {                                                          \
    atomicAdd(&acc[cur * DIM + g * 4 + 0], sum.x);           \
    atomicAdd(&acc[cur * DIM + g * 4 + 1], sum.y);           \
    atomicAdd(&acc[cur * DIM + g * 4 + 2], sum.z);           \
    atomicAdd(&acc[cur * DIM + g * 4 + 3], sum.w);           \
    atomicAdd(&acc[NDOM * DIM + cur * DIM + g * 4 + 0], sq.x); \
    atomicAdd(&acc[NDOM * DIM + cur * DIM + g * 4 + 1], sq.y); \
    atomicAdd(&acc[NDOM * DIM + cur * DIM + g * 4 + 2], sq.z); \
    atomicAdd(&acc[NDOM * DIM + cur * DIM + g * 4 + 3], sq.w); \
    if (g == 0) atomicAdd(&lcnt[cur], cnt);                  \
    sum = make_float4(0.f, 0.f, 0.f, 0.f);                   \
    sq = make_float4(0.f, 0.f, 0.f, 0.f);                    \
    cnt = 0.f;                                               \
  }
#define ACC(V)                                               \
  {                                                          \
    sum.x += (V).x; sum.y += (V).y;                          \
    sum.z += (V).z; sum.w += (V).w;                          \
    sq.x = fmaf((V).x, (V).x, sq.x);                         \
    sq.y = fmaf((V).y, (V).y, sq.y);                         \
    sq.z = fmaf((V).z, (V).z, sq.z);                         \
    sq.w = fmaf((V).w, (V).w, sq.w);                         \
    cnt += 1.f;                                              \
  }

  for (int i = 0; i < rowsPerHW; i += 4) {
    const int p0 = perm[base + i + 0];
    const int p1 = perm[base + i + 1];
    const int p2 = perm[base + i + 2];
    const int p3 = perm[base + i + 3];
    const int s0 = seg[p0];
    const int s1 = seg[p1];
    const int s2 = seg[p2];
    const int s3 = seg[p3];
    // 4 independent 512B row loads in flight (sorted -> rows scattered within
    // a 2048-row window; each load itself fully coalesced)
    const float4 v0 = x4[(size_t)p0 * 32 + g];
    const float4 v1 = x4[(size_t)p1 * 32 + g];
    const float4 v2 = x4[(size_t)p2 * 32 + g];
    const float4 v3 = x4[(size_t)p3 * 32 + g];
    if (s0 != cur) { FLUSH(); cur = s0; }
    ACC(v0)
    if (s1 != cur) { FLUSH(); cur = s1; }
    ACC(v1)
    if (s2 != cur) { FLUSH(); cur = s2; }
    ACC(v2)
    if (s3 != cur) { FLUSH(); cur = s3; }
    ACC(v3)
  }
  FLUSH();
#undef ACC
#undef FLUSH
  __syncthreads();

  float* outp = partials + (size_t)blockIdx.x * PENT;
  if (tid < NDOM) outp[tid] = lcnt[tid];
  for (int i = tid; i < 2 * NDOM * DIM; i += 256) outp[NDOM + i] = acc[i];
}

// ---------------- pass 2a: reduce NB partial rows -> 64 ----------------
__global__ __launch_bounds__(256) void pn_reduce2(const float* __restrict__ partials,
                                                  float* __restrict__ partials2,
                                                  int NB) {
  const int b = blockIdx.x;  // 0..63
  const int per = NB >> 6;
  const int b0 = b * per;
  const int tid = threadIdx.x;
  float acc[9];
#pragma unroll
  for (int i = 0; i < 9; ++i) acc[i] = 0.f;
  for (int j = b0; j < b0 + per; ++j) {
    const float* p = partials + (size_t)j * PENT;
#pragma unroll
    for (int i = 0; i < 9; ++i) {
      const int e = tid + i * 256;
      if (e < PENT) acc[i] += p[e];
    }
  }
  float* o = partials2 + (size_t)b * PENT;
#pragma unroll
  for (int i = 0; i < 9; ++i) {
    const int e = tid + i * 256;
    if (e < PENT) o[e] = acc[i];
  }
}

// ---------------- pass 2b: final reduce + scale/shift table (4 blocks) ----------------
__global__ __launch_bounds__(256) void pn_finalize(const float* __restrict__ partials2,
                                                   const float* __restrict__ gg,
                                                   const float* __restrict__ gb,
                                                   const float* __restrict__ dg,
                                                   const float* __restrict__ db,
                                                   float* __restrict__ stats) {
  const int t = blockIdx.x * 256 + threadIdx.x;  // (k = t>>7, d = t&127)
  const int k = t >> 7;
  const int d = t & (DIM - 1);
  float c = 0.f, s = 0.f, q = 0.f;
  for (int j = 0; j < 64; ++j) {
    const float* p = partials2 + (size_t)j * PENT;
    c += p[k];
    s += p[NDOM + t];
    q += p[NDOM + NDOM * DIM + t];
  }
  const float n = fmaxf(c, 1.f);
  const float mean = s / n;
  const float var = fmaxf(q / n - mean * mean, 0.f);
  const float rstd = rsqrtf(var + EPSV);
  const float scale = (gg[d] + dg[t]) * rstd;  // dg[k*128+d] == dg[t]
  const float shift = (gb[d] + db[t]) - scale * mean;
  stats[t] = scale;
  stats[NDOM * DIM + t] = shift;
}

// ---------------- pass 3: normalize (one-shot, 1 float4/thread) ----------------
__global__ __launch_bounds__(256) void pn_apply(const float* __restrict__ x,
                                                const int* __restrict__ seg,
                                                const float* __restrict__ stats,
                                                float* __restrict__ out) {
  const int g = blockIdx.x * 256 + threadIdx.x;  // float4 index
  const int row = g >> 5;                        // 32 float4 per row
  const int c4 = g & 31;
  const int s = seg[row];
  const float4 xv = ((const float4*)x)[g];
  const float4 a = ((const float4*)(stats + s * DIM))[c4];
  const float4 b = ((const float4*)(stats + NDOM * DIM + s * DIM))[c4];
  float4 o;
  o.x = fmaf(xv.x, a.x, b.x);
  o.y = fmaf(xv.y, a.y, b.y);
  o.z = fmaf(xv.z, a.z, b.z);
  o.w = fmaf(xv.w, a.w, b.w);
  ((float4*)out)[g] = o;
}

extern "C" void kernel_launch(void* const* d_in, const int* in_sizes, int n_in,
                              void* d_out, int out_size, void* d_ws, size_t ws_size,
                              hipStream_t stream) {
  const float* x = (const float*)d_in[0];
  const float* gg = (const float*)d_in[1];
  const float* gb = (const float*)d_in[2];
  const float* dg = (const float*)d_in[3];
  const float* db = (const float*)d_in[4];
  const int* seg = (const int*)d_in[5];
  float* out = (float*)d_out;
  const int B = in_sizes[5];  // 262144

  // workspace: perm[B] int | partials[NB][PENT] | partials2[64][PENT] | stats
  const int NB = 512;
  int* perm = (int*)d_ws;
  float* partials = (float*)(perm + B);
  float* partials2 = partials + (size_t)NB * PENT;
  float* stats = partials2 + (size_t)64 * PENT;

  const int rpb = B / NB;  // 512 rows/block; 64 rows per half-wave

  pn_sort<<<B / SORT_ROWS, 256, 0, stream>>>(seg, perm);
  pn_reduce<<<NB, 256, 0, stream>>>((const float4*)x, seg, perm, partials, rpb);
  pn_reduce2<<<64, 256, 0, stream>>>(partials, partials2, NB);
  pn_finalize<<<4, 256, 0, stream>>>(partials2, gg, gb, dg, db, stats);

  const int nblk = (B * (DIM / 4)) / 256;  // 32768
  pn_apply<<<nblk, 256, 0, stream>>>(x, seg, stats, out);
}